// Round 9
// baseline (187.169 us; speedup 1.0000x reference)
//
#include <hip/hip_runtime.h>
#include <hip/hip_bf16.h>
#include <cstddef>

#define BN 4096
#define DD 128
#define NSTEPS 100
#define PTILE 128
#define PLSTR 136   // bf16 elems per LDS row: 128 + 8 pad -> 272 B stride (16B-aligned)
#define GRID_T (BN / PTILE)   // 32
#define HSLOT 101   // floats per histogram slot; 101 mod 32 = 5, coprime with 32 -> full bank spread
#define NREP 16     // histogram replicas (slot pairs); 32 slots total (pos/neg interleaved)

typedef __attribute__((ext_vector_type(8))) short bf16x8;
typedef __attribute__((ext_vector_type(4))) float f32x4;

// unsafeAtomicAdd emits HW fp atomics (ds_add_f32 / global_atomic_add_f32);
// default atomicAdd(float*) lowers to a CAS loop (denormal-safe path) — the
// r2/r3/r6 173-176us invariant at 16.8M LDS atomics is that CAS loop.
__device__ __forceinline__ void faddf(float* p, float v) {
    unsafeAtomicAdd(p, v);
}

// ---------------- normalize + convert to bf16: one wave per row ----------------
__global__ __launch_bounds__(256) void hl_normalize(const float* __restrict__ emb,
                                                    ushort* __restrict__ out) {
    int w = threadIdx.x >> 6;
    int lane = threadIdx.x & 63;
    int row = (blockIdx.x << 2) + w;
    const float2 v = *(const float2*)(emb + (size_t)row * DD + 2 * lane);
    float ss = v.x * v.x + v.y * v.y;
    #pragma unroll
    for (int off = 32; off > 0; off >>= 1) ss += __shfl_xor(ss, off);
    float inv = 1.0f / sqrtf(ss);
    __hip_bfloat16 b0 = __float2bfloat16(v.x * inv);
    __hip_bfloat16 b1 = __float2bfloat16(v.y * inv);
    ushort2 pk;
    pk.x = *(ushort*)&b0;
    pk.y = *(ushort*)&b1;
    *(ushort2*)(out + (size_t)row * DD + 2 * lane) = pk;
}

// ---------------- pair kernel: 128x128 tile pairs via bf16 MFMA ----------------
// gHist layout: [0..99] = pos bins, [100..199] = neg bins
__global__ __launch_bounds__(256, 2) void hl_pair(const ushort* __restrict__ nemb,
                                                  const int* __restrict__ cls,
                                                  float* __restrict__ gHist) {
    const int ti = blockIdx.y, tj = blockIdx.x;
    if (ti > tj) return;

    // arena: tiles during MFMA phase, replicated histograms afterwards
    __shared__ __align__(16) char arena[2 * PTILE * PLSTR * sizeof(ushort)];  // 69632 B
    ushort* As = (ushort*)arena;
    ushort* Bs = As + PTILE * PLSTR;
    float* hrep = (float*)arena;               // 2*NREP slots * HSLOT floats = 12928 B

    __shared__ int clsA[PTILE], clsB[PTILE];

    const int tid = threadIdx.x;
    if (tid < PTILE) clsA[tid] = cls[ti * PTILE + tid];
    else             clsB[tid - PTILE] = cls[tj * PTILE + (tid - PTILE)];

    // stage A and B tiles: 128 rows x 16 chunks of 16B each, per matrix -> 8 iters each
    #pragma unroll
    for (int it = 0; it < 8; ++it) {
        int idx = it * 256 + tid;        // 0..2047
        int row = idx >> 4;              // 0..127
        int c = idx & 15;                // 0..15 (16B chunks)
        const float4 va = *(const float4*)(nemb + (size_t)(ti * PTILE + row) * DD + c * 8);
        const float4 vb = *(const float4*)(nemb + (size_t)(tj * PTILE + row) * DD + c * 8);
        *(float4*)(&As[row * PLSTR + c * 8]) = va;
        *(float4*)(&Bs[row * PLSTR + c * 8]) = vb;
    }
    __syncthreads();

    const int lane = tid & 63;
    const int wid = tid >> 6;            // 0..3
    const int wr = wid >> 1, wc = wid & 1;
    const int lr = lane & 15;
    const int kg = lane >> 4;            // 0..3

    f32x4 zero4 = {0.f, 0.f, 0.f, 0.f};
    f32x4 acc[4][4];
    #pragma unroll
    for (int a = 0; a < 4; ++a)
        #pragma unroll
        for (int b = 0; b < 4; ++b) acc[a][b] = zero4;

    #pragma unroll
    for (int ks = 0; ks < 4; ++ks) {
        bf16x8 af[4], bfr[4];
        #pragma unroll
        for (int f = 0; f < 4; ++f) {
            int arow = wr * 64 + f * 16 + lr;
            af[f] = *(const bf16x8*)(&As[arow * PLSTR + ks * 32 + kg * 8]);
            int brow = wc * 64 + f * 16 + lr;
            bfr[f] = *(const bf16x8*)(&Bs[brow * PLSTR + ks * 32 + kg * 8]);
        }
        #pragma unroll
        for (int fa = 0; fa < 4; ++fa)
            #pragma unroll
            for (int fb = 0; fb < 4; ++fb)
                acc[fa][fb] = __builtin_amdgcn_mfma_f32_16x16x32_bf16(af[fa], bfr[fb], acc[fa][fb], 0, 0, 0);
    }

    // tiles are dead now; repurpose arena as replicated histograms
    __syncthreads();
    #pragma unroll
    for (int i = tid; i < 2 * NREP * HSLOT; i += 256) hrep[i] = 0.f;
    __syncthreads();

    // ---- histogram epilogue from acc registers ----
    constexpr float STEPF = 2.0f / 99.0f;
    constexpr float INVSTEP = 49.5f;
    constexpr float CLIPV = 1.0f - 1e-6f;

    // D[fa][fb] reg j of lane: row = wr*64 + fa*16 + (lane>>4)*4 + j, col = wc*64 + fb*16 + (lane&15)
    const int li_base = wr * 64 + (kg << 2);
    const int lj_base = wc * 64 + lr;
    const int rep2 = (lane & 15) << 1;   // replica pair base (slot = rep2 | isNeg)

    int ca[16];
    #pragma unroll
    for (int fa = 0; fa < 4; ++fa)
        #pragma unroll
        for (int j = 0; j < 4; ++j) ca[fa * 4 + j] = clsA[li_base + fa * 16 + j];

    const bool offdiag = (ti != tj);

    #pragma unroll
    for (int fb = 0; fb < 4; ++fb) {
        const int lj = lj_base + fb * 16;
        const int cb = clsB[lj];
        #pragma unroll
        for (int fa = 0; fa < 4; ++fa) {
            const int li0 = li_base + fa * 16;
            f32x4 v = acc[fa][fb];
            #pragma unroll
            for (int j = 0; j < 4; ++j) {
                const int li = li0 + j;
                if (offdiag || li < lj) {
                    float s = v[j];
                    s = fminf(fmaxf(s, -CLIPV), CLIPV);
                    float u = (s + CLIPV) * INVSTEP;
                    int jb = (int)u;
                    if (jb > 98) jb = 98;
                    float t_j = (float)jb * STEPF - 1.0f;
                    float w_hi = (s - t_j) * INVSTEP;
                    float w_lo = 1.0f - w_hi;
                    int slot = rep2 | (int)(ca[fa * 4 + j] != cb);   // even=pos, odd=neg
                    int idx = slot * HSLOT + jb;
                    faddf(&hrep[idx], w_lo);
                    faddf(&hrep[idx + 1], w_hi);
                }
            }
        }
    }
    __syncthreads();

    // reduce replicas -> one global atomic per (half, bin)
    if (tid < 2 * NSTEPS) {
        int h = tid >= NSTEPS;               // 0=pos, 1=neg
        int b = tid - h * NSTEPS;
        float ssum = 0.f;
        #pragma unroll
        for (int r = 0; r < NREP; ++r) ssum += hrep[((r << 1) | h) * HSLOT + b];
        faddf(&gHist[h * NSTEPS + b], ssum);
    }
}

// ---------------- finalize: cumsum + dot, 128-thread scan ----------------
__global__ __launch_bounds__(128) void hl_final(const float* __restrict__ gHist,
                                                float* __restrict__ out) {
    __shared__ float spA[128], snA[128], sc[128], red[128];
    const int t = threadIdx.x;
    float p = (t < NSTEPS) ? gHist[t] : 0.f;
    float n = (t < NSTEPS) ? gHist[NSTEPS + t] : 0.f;
    spA[t] = p; snA[t] = n;
    __syncthreads();
    #pragma unroll
    for (int off = 64; off > 0; off >>= 1) {
        if (t < off) { spA[t] += spA[t + off]; snA[t] += snA[t + off]; }
        __syncthreads();
    }
    const float sp = spA[0], sn = snA[0];
    // inclusive prefix sum of p (Hillis-Steele)
    sc[t] = p;
    __syncthreads();
    #pragma unroll
    for (int off = 1; off < 128; off <<= 1) {
        float v = (t >= off) ? sc[t - off] : 0.f;
        __syncthreads();
        sc[t] += v;
        __syncthreads();
    }
    red[t] = n * sc[t];
    __syncthreads();
    #pragma unroll
    for (int off = 64; off > 0; off >>= 1) {
        if (t < off) red[t] += red[t + off];
        __syncthreads();
    }
    if (t == 0) out[0] = red[0] / (sp * sn);
}

extern "C" void kernel_launch(void* const* d_in, const int* in_sizes, int n_in,
                              void* d_out, int out_size, void* d_ws, size_t ws_size,
                              hipStream_t stream) {
    const float* emb = (const float*)d_in[0];
    const int* classes = (const int*)d_in[1];
    float* out = (float*)d_out;

    ushort* nemb = (ushort*)d_ws;                                 // 4096*128 bf16 = 1 MB
    float* gHist = (float*)((char*)d_ws + (size_t)BN * DD * sizeof(ushort));  // 200 floats

    hipMemsetAsync(gHist, 0, 2 * NSTEPS * sizeof(float), stream);

    hl_normalize<<<BN / 4, 256, 0, stream>>>(emb, nemb);

    dim3 grid(GRID_T, GRID_T);  // 32 x 32; blocks with ti>tj early-exit
    hl_pair<<<grid, 256, 0, stream>>>(nemb, classes, gHist);

    hl_final<<<1, 128, 0, stream>>>(gHist, out);
}

// Round 10
// 75.775 us; speedup vs baseline: 2.4701x; 2.4701x over previous
//
#include <hip/hip_runtime.h>
#include <hip/hip_bf16.h>
#include <cstddef>

#define BN 4096
#define DD 128
#define NSTEPS 100
#define PTILE 128
#define PLSTR 136   // bf16 elems per LDS row: 128 + 8 pad -> 272 B stride
#define GRID_T (BN / PTILE)   // 32
#define HSLOT 101   // floats per POS-histogram slot; coprime with 32 banks
#define NREP 16     // POS histogram replicas (keyed by lane&15)

typedef __attribute__((ext_vector_type(8))) short bf16x8;
typedef __attribute__((ext_vector_type(4))) float f32x4;

// HW fp atomic (ds_add_f32 / global_atomic_add_f32). Measured (r2-r9): LDS
// fp-atomic lane-ops cost ~6.3 cyc CU-serialized regardless of address
// pattern -> use atomics ONLY for the rare POS path (~1% of pairs).
__device__ __forceinline__ void faddf(float* p, float v) {
    unsafeAtomicAdd(p, v);
}

// ---------------- normalize + convert to bf16: one wave per row ----------------
__global__ __launch_bounds__(256) void hl_normalize(const float* __restrict__ emb,
                                                    ushort* __restrict__ out) {
    int w = threadIdx.x >> 6;
    int lane = threadIdx.x & 63;
    int row = (blockIdx.x << 2) + w;
    const float2 v = *(const float2*)(emb + (size_t)row * DD + 2 * lane);
    float ss = v.x * v.x + v.y * v.y;
    #pragma unroll
    for (int off = 32; off > 0; off >>= 1) ss += __shfl_xor(ss, off);
    float inv = 1.0f / sqrtf(ss);
    __hip_bfloat16 b0 = __float2bfloat16(v.x * inv);
    __hip_bfloat16 b1 = __float2bfloat16(v.y * inv);
    ushort2 pk;
    pk.x = *(ushort*)&b0;
    pk.y = *(ushort*)&b1;
    *(ushort2*)(out + (size_t)row * DD + 2 * lane) = pk;
}

// ---------------- pair kernel: 128x128 tile pairs via bf16 MFMA ----------------
// gHist layout: [0..99] = ALL bins, [100..199] = POS bins  (neg = all - pos)
__global__ __launch_bounds__(256, 1) void hl_pair(const ushort* __restrict__ nemb,
                                                  const int* __restrict__ cls,
                                                  float* __restrict__ gHist) {
    const int ti = blockIdx.y, tj = blockIdx.x;
    if (ti > tj) return;

    // arena: tiles (69632 B) during MFMA, per-thread ALL-hist (102400 B) after
    __shared__ __align__(16) char arena[NSTEPS * 256 * sizeof(float)];  // 102400 B
    ushort* As = (ushort*)arena;
    ushort* Bs = As + PTILE * PLSTR;
    float* hall = (float*)arena;                  // [bin][256] per-thread columns
    __shared__ float hpos[NREP * HSLOT];          // 6464 B, atomic POS path
    __shared__ int clsA[PTILE], clsB[PTILE];

    const int tid = threadIdx.x;
    if (tid < PTILE) clsA[tid] = cls[ti * PTILE + tid];
    else             clsB[tid - PTILE] = cls[tj * PTILE + (tid - PTILE)];

    // stage A and B tiles: 128 rows x 16 chunks of 16B each, per matrix
    #pragma unroll
    for (int it = 0; it < 8; ++it) {
        int idx = it * 256 + tid;
        int row = idx >> 4;
        int c = idx & 15;
        const float4 va = *(const float4*)(nemb + (size_t)(ti * PTILE + row) * DD + c * 8);
        const float4 vb = *(const float4*)(nemb + (size_t)(tj * PTILE + row) * DD + c * 8);
        *(float4*)(&As[row * PLSTR + c * 8]) = va;
        *(float4*)(&Bs[row * PLSTR + c * 8]) = vb;
    }
    __syncthreads();

    const int lane = tid & 63;
    const int wid = tid >> 6;
    const int wr = wid >> 1, wc = wid & 1;
    const int lr = lane & 15;
    const int kg = lane >> 4;

    f32x4 zero4 = {0.f, 0.f, 0.f, 0.f};
    f32x4 acc[4][4];
    #pragma unroll
    for (int a = 0; a < 4; ++a)
        #pragma unroll
        for (int b = 0; b < 4; ++b) acc[a][b] = zero4;

    #pragma unroll
    for (int ks = 0; ks < 4; ++ks) {
        bf16x8 af[4], bfr[4];
        #pragma unroll
        for (int f = 0; f < 4; ++f) {
            int arow = wr * 64 + f * 16 + lr;
            af[f] = *(const bf16x8*)(&As[arow * PLSTR + ks * 32 + kg * 8]);
            int brow = wc * 64 + f * 16 + lr;
            bfr[f] = *(const bf16x8*)(&Bs[brow * PLSTR + ks * 32 + kg * 8]);
        }
        #pragma unroll
        for (int fa = 0; fa < 4; ++fa)
            #pragma unroll
            for (int fb = 0; fb < 4; ++fb)
                acc[fa][fb] = __builtin_amdgcn_mfma_f32_16x16x32_bf16(af[fa], bfr[fb], acc[fa][fb], 0, 0, 0);
    }

    // tiles dead; zero ALL-hist (overlay) and POS-hist
    __syncthreads();
    #pragma unroll 4
    for (int i = tid; i < NSTEPS * 256; i += 256) hall[i] = 0.f;
    for (int i = tid; i < NREP * HSLOT; i += 256) hpos[i] = 0.f;
    __syncthreads();

    // ---- histogram epilogue: non-atomic per-thread ALL, atomic rare POS ----
    constexpr float STEPF = 2.0f / 99.0f;
    constexpr float INVSTEP = 49.5f;
    constexpr float CLIPV = 1.0f - 1e-6f;

    const int li_base = wr * 64 + (kg << 2);
    const int lj_base = wc * 64 + lr;
    const int posrep = (lane & 15) * HSLOT;

    int ca[16];
    #pragma unroll
    for (int fa = 0; fa < 4; ++fa)
        #pragma unroll
        for (int j = 0; j < 4; ++j) ca[fa * 4 + j] = clsA[li_base + fa * 16 + j];

    const bool offdiag = (ti != tj);

    #pragma unroll
    for (int fb = 0; fb < 4; ++fb) {
        const int lj = lj_base + fb * 16;
        const int cb = clsB[lj];
        #pragma unroll
        for (int fa = 0; fa < 4; ++fa) {
            const int li0 = li_base + fa * 16;
            f32x4 v = acc[fa][fb];
            #pragma unroll
            for (int j = 0; j < 4; ++j) {
                const int li = li0 + j;
                if (offdiag || li < lj) {
                    float s = v[j];
                    s = fminf(fmaxf(s, -CLIPV), CLIPV);
                    float u = (s + CLIPV) * INVSTEP;
                    int jb = (int)u;
                    if (jb > 98) jb = 98;
                    float t_j = (float)jb * STEPF - 1.0f;
                    float w_hi = (s - t_j) * INVSTEP;
                    float w_lo = 1.0f - w_hi;
                    int base = jb * 256 + tid;          // own column: no race
                    hall[base] += w_lo;                 // plain ds_read/ds_write
                    hall[base + 256] += w_hi;
                    if (ca[fa * 4 + j] == cb) {         // ~1% of pairs
                        faddf(&hpos[posrep + jb], w_lo);
                        faddf(&hpos[posrep + jb + 1], w_hi);
                    }
                }
            }
        }
    }
    __syncthreads();

    // reduce: bin b of ALL summed by threads b (r 0..127) and b+128 (r 128..255),
    // staggered (r+b)&255 indexing -> per-wave distinct banks
    if (tid < NSTEPS) {
        const int b = tid;
        float ssum = 0.f;
        #pragma unroll 8
        for (int r = 0; r < 128; ++r) ssum += hall[b * 256 + ((r + b) & 255)];
        faddf(&gHist[b], ssum);
        float psum = 0.f;
        #pragma unroll
        for (int rp = 0; rp < NREP; ++rp) psum += hpos[rp * HSLOT + b];
        faddf(&gHist[NSTEPS + b], psum);
    } else if (tid >= 128 && tid < 128 + NSTEPS) {
        const int b = tid - 128;
        float ssum = 0.f;
        #pragma unroll 8
        for (int r = 128; r < 256; ++r) ssum += hall[b * 256 + ((r + b) & 255)];
        faddf(&gHist[b], ssum);
    }
}

// ---------------- finalize: cumsum + dot, 128-thread scan ----------------
__global__ __launch_bounds__(128) void hl_final(const float* __restrict__ gHist,
                                                float* __restrict__ out) {
    __shared__ float spA[128], snA[128], sc[128], red[128];
    const int t = threadIdx.x;
    float p = (t < NSTEPS) ? gHist[NSTEPS + t] : 0.f;            // POS
    float n = (t < NSTEPS) ? (gHist[t] - gHist[NSTEPS + t]) : 0.f;  // NEG = ALL - POS
    spA[t] = p; snA[t] = n;
    __syncthreads();
    #pragma unroll
    for (int off = 64; off > 0; off >>= 1) {
        if (t < off) { spA[t] += spA[t + off]; snA[t] += snA[t + off]; }
        __syncthreads();
    }
    const float sp = spA[0], sn = snA[0];
    // inclusive prefix sum of p (Hillis-Steele)
    sc[t] = p;
    __syncthreads();
    #pragma unroll
    for (int off = 1; off < 128; off <<= 1) {
        float v = (t >= off) ? sc[t - off] : 0.f;
        __syncthreads();
        sc[t] += v;
        __syncthreads();
    }
    red[t] = n * sc[t];
    __syncthreads();
    #pragma unroll
    for (int off = 64; off > 0; off >>= 1) {
        if (t < off) red[t] += red[t + off];
        __syncthreads();
    }
    if (t == 0) out[0] = red[0] / (sp * sn);
}

extern "C" void kernel_launch(void* const* d_in, const int* in_sizes, int n_in,
                              void* d_out, int out_size, void* d_ws, size_t ws_size,
                              hipStream_t stream) {
    const float* emb = (const float*)d_in[0];
    const int* classes = (const int*)d_in[1];
    float* out = (float*)d_out;

    ushort* nemb = (ushort*)d_ws;                                 // 4096*128 bf16 = 1 MB
    float* gHist = (float*)((char*)d_ws + (size_t)BN * DD * sizeof(ushort));  // 200 floats

    hipMemsetAsync(gHist, 0, 2 * NSTEPS * sizeof(float), stream);

    hl_normalize<<<BN / 4, 256, 0, stream>>>(emb, nemb);

    dim3 grid(GRID_T, GRID_T);  // 32 x 32; blocks with ti>tj early-exit
    hl_pair<<<grid, 256, 0, stream>>>(nemb, classes, gHist);

    hl_final<<<1, 128, 0, stream>>>(gHist, out);
}

// Round 14
// 62.075 us; speedup vs baseline: 3.0152x; 1.2207x over previous
//
#include <hip/hip_runtime.h>
#include <hip/hip_bf16.h>
#include <hip/hip_fp16.h>
#include <cstddef>

#define BN 4096
#define DD 128
#define NSTEPS 100
#define PTILE 128
#define PLSTR 136   // bf16 elems per LDS row: 128 + 8 pad -> 272 B stride
#define GRID_T (BN / PTILE)   // 32
#define NOFF 496    // strictly-upper tile pairs (ti<tj)
#define NBLK 528    // + 32 diagonal tiles
#define HSLOT 101   // floats per POS-histogram slot
#define NREP 16     // POS histogram replicas (keyed by lane&15)

typedef __attribute__((ext_vector_type(8))) short bf16x8;
typedef __attribute__((ext_vector_type(4))) float f32x4;

// HW fp atomic. Measured (r2-r9): LDS fp-atomic lane-ops ~6.3 cyc CU-serialized
// regardless of address pattern -> atomics ONLY on the rare (~1%) POS path.
__device__ __forceinline__ void faddf(float* p, float v) {
    unsafeAtomicAdd(p, v);
}

// ---------------- normalize + convert to bf16: one wave per row ----------------
__global__ __launch_bounds__(256) void hl_normalize(const float* __restrict__ emb,
                                                    ushort* __restrict__ out) {
    int w = threadIdx.x >> 6;
    int lane = threadIdx.x & 63;
    int row = (blockIdx.x << 2) + w;
    const float2 v = *(const float2*)(emb + (size_t)row * DD + 2 * lane);
    float ss = v.x * v.x + v.y * v.y;
    #pragma unroll
    for (int off = 32; off > 0; off >>= 1) ss += __shfl_xor(ss, off);
    float inv = 1.0f / sqrtf(ss);
    __hip_bfloat16 b0 = __float2bfloat16(v.x * inv);
    __hip_bfloat16 b1 = __float2bfloat16(v.y * inv);
    ushort2 pk;
    pk.x = *(ushort*)&b0;
    pk.y = *(ushort*)&b1;
    *(ushort2*)(out + (size_t)row * DD + 2 * lane) = pk;
}

// ---------------- pair kernel: 128x128 tile pairs via bf16 MFMA ----------------
// gHist layout: [0..99] = ALL bins, [100..199] = POS bins  (neg = all - pos)
__global__ __launch_bounds__(256, 2) void hl_pair(const ushort* __restrict__ nemb,
                                                  const int* __restrict__ cls,
                                                  float* __restrict__ gHist) {
    // flat grid: blocks 0..495 = strictly-upper tile pairs, 496..527 = diagonal
    int ti, tj;
    {
        int t = blockIdx.x;
        if (t < NOFF) {
            ti = 0;
            int rem = t;
            while (rem >= GRID_T - 1 - ti) { rem -= GRID_T - 1 - ti; ++ti; }
            tj = ti + 1 + rem;
        } else {
            ti = tj = t - NOFF;
        }
    }

    // arena: tiles (69632 B) during MFMA; per-thread fp16 ALL-hist (51200 B) after
    __shared__ __align__(16) char arena[2 * PTILE * PLSTR * sizeof(ushort)];
    ushort* As = (ushort*)arena;
    ushort* Bs = As + PTILE * PLSTR;
    _Float16* hallh = (_Float16*)arena;           // [bin][256] per-thread columns
    uint* hall32 = (uint*)arena;                  // same, as uint pairs
    __shared__ float hpos[NREP * HSLOT];          // 6464 B, fp32 atomic POS path
    __shared__ int clsA[PTILE], clsB[PTILE];

    const int tid = threadIdx.x;
    if (tid < PTILE) clsA[tid] = cls[ti * PTILE + tid];
    else             clsB[tid - PTILE] = cls[tj * PTILE + (tid - PTILE)];

    // stage A and B tiles
    #pragma unroll
    for (int it = 0; it < 8; ++it) {
        int idx = it * 256 + tid;
        int row = idx >> 4;
        int c = idx & 15;
        const float4 va = *(const float4*)(nemb + (size_t)(ti * PTILE + row) * DD + c * 8);
        const float4 vb = *(const float4*)(nemb + (size_t)(tj * PTILE + row) * DD + c * 8);
        *(float4*)(&As[row * PLSTR + c * 8]) = va;
        *(float4*)(&Bs[row * PLSTR + c * 8]) = vb;
    }
    __syncthreads();

    const int lane = tid & 63;
    const int wid = tid >> 6;
    const int wr = wid >> 1, wc = wid & 1;
    const int lr = lane & 15;
    const int kg = lane >> 4;

    f32x4 zero4 = {0.f, 0.f, 0.f, 0.f};
    f32x4 acc[4][4];
    #pragma unroll
    for (int a = 0; a < 4; ++a)
        #pragma unroll
        for (int b = 0; b < 4; ++b) acc[a][b] = zero4;

    #pragma unroll
    for (int ks = 0; ks < 4; ++ks) {
        bf16x8 af[4], bfr[4];
        #pragma unroll
        for (int f = 0; f < 4; ++f) {
            int arow = wr * 64 + f * 16 + lr;
            af[f] = *(const bf16x8*)(&As[arow * PLSTR + ks * 32 + kg * 8]);
            int brow = wc * 64 + f * 16 + lr;
            bfr[f] = *(const bf16x8*)(&Bs[brow * PLSTR + ks * 32 + kg * 8]);
        }
        #pragma unroll
        for (int fa = 0; fa < 4; ++fa)
            #pragma unroll
            for (int fb = 0; fb < 4; ++fb)
                acc[fa][fb] = __builtin_amdgcn_mfma_f32_16x16x32_bf16(af[fa], bfr[fb], acc[fa][fb], 0, 0, 0);
    }

    // tiles dead; zero fp16 ALL-hist (overlay) and POS-hist
    __syncthreads();
    #pragma unroll 8
    for (int i = tid; i < NSTEPS * 128; i += 256) hall32[i] = 0u;   // 51200 B as uints
    for (int i = tid; i < NREP * HSLOT; i += 256) hpos[i] = 0.f;
    __syncthreads();

    // ---- histogram epilogue: branch-free fp16 per-thread ALL, atomic rare POS ----
    constexpr float STEPF = 2.0f / 99.0f;
    constexpr float INVSTEP = 49.5f;
    constexpr float CLIPV = 1.0f - 1e-6f;

    const int li_base = wr * 64 + (kg << 2);
    const int lj_base = wc * 64 + lr;
    const int posrep = (lane & 15) * HSLOT;

    int ca[16];
    #pragma unroll
    for (int fa = 0; fa < 4; ++fa)
        #pragma unroll
        for (int j = 0; j < 4; ++j) ca[fa * 4 + j] = clsA[li_base + fa * 16 + j];

    const bool offdiag = (ti != tj);

    #pragma unroll
    for (int fb = 0; fb < 4; ++fb) {
        const int lj = lj_base + fb * 16;
        const int cb = clsB[lj];
        #pragma unroll
        for (int fa = 0; fa < 4; ++fa) {
            const int li0 = li_base + fa * 16;
            f32x4 v = acc[fa][fb];
            #pragma unroll
            for (int j = 0; j < 4; ++j) {
                const int li = li0 + j;
                const bool valid = offdiag || (li < lj);
                float s = v[j];
                s = fminf(fmaxf(s, -CLIPV), CLIPV);
                float u = (s + CLIPV) * INVSTEP;
                int jb = (int)u;
                if (jb > 98) jb = 98;
                float t_j = (float)jb * STEPF - 1.0f;
                float vm = valid ? 1.0f : 0.0f;          // mask into weights: no branch
                float w_hi = (s - t_j) * INVSTEP * vm;
                float w_lo = vm - w_hi;
                int base = jb * 256 + tid;               // own column: no race
                _Float16 lo = hallh[base];
                _Float16 hi = hallh[base + 256];
                hallh[base] = lo + (_Float16)w_lo;       // plain ds_read/ds_write
                hallh[base + 256] = hi + (_Float16)w_hi;
                if (valid && ca[fa * 4 + j] == cb) {     // ~1% of pairs
                    faddf(&hpos[posrep + jb], w_lo);
                    faddf(&hpos[posrep + jb + 1], w_hi);
                }
            }
        }
    }
    __syncthreads();

    // reduce: bin b summed by threads b (cols 0..127) and b+128 (cols 128..255),
    // staggered (r+b)&127 uint indexing -> conflict-free
    if (tid < NSTEPS) {
        const int b = tid;
        float ssum = 0.f;
        #pragma unroll 8
        for (int r = 0; r < 64; ++r) {
            uint u2 = hall32[b * 128 + ((r + b) & 127)];
            __half2 h2 = *(__half2*)&u2;
            ssum += __low2float(h2) + __high2float(h2);
        }
        faddf(&gHist[b], ssum);
        float psum = 0.f;
        #pragma unroll
        for (int rp = 0; rp < NREP; ++rp) psum += hpos[rp * HSLOT + b];
        faddf(&gHist[NSTEPS + b], psum);
    } else if (tid >= 128 && tid < 128 + NSTEPS) {
        const int b = tid - 128;
        float ssum = 0.f;
        #pragma unroll 8
        for (int r = 64; r < 128; ++r) {
            uint u2 = hall32[b * 128 + ((r + b) & 127)];
            __half2 h2 = *(__half2*)&u2;
            ssum += __low2float(h2) + __high2float(h2);
        }
        faddf(&gHist[b], ssum);
    }
}

// ---------------- finalize: cumsum + dot, 128-thread scan ----------------
__global__ __launch_bounds__(128) void hl_final(const float* __restrict__ gHist,
                                                float* __restrict__ out) {
    __shared__ float spA[128], snA[128], sc[128], red[128];
    const int t = threadIdx.x;
    float p = (t < NSTEPS) ? gHist[NSTEPS + t] : 0.f;               // POS
    float n = (t < NSTEPS) ? (gHist[t] - gHist[NSTEPS + t]) : 0.f;  // NEG = ALL - POS
    spA[t] = p; snA[t] = n;
    __syncthreads();
    #pragma unroll
    for (int off = 64; off > 0; off >>= 1) {
        if (t < off) { spA[t] += spA[t + off]; snA[t] += snA[t + off]; }
        __syncthreads();
    }
    const float sp = spA[0], sn = snA[0];
    sc[t] = p;
    __syncthreads();
    #pragma unroll
    for (int off = 1; off < 128; off <<= 1) {
        float v = (t >= off) ? sc[t - off] : 0.f;
        __syncthreads();
        sc[t] += v;
        __syncthreads();
    }
    red[t] = n * sc[t];
    __syncthreads();
    #pragma unroll
    for (int off = 64; off > 0; off >>= 1) {
        if (t < off) red[t] += red[t + off];
        __syncthreads();
    }
    if (t == 0) out[0] = red[0] / (sp * sn);
}

extern "C" void kernel_launch(void* const* d_in, const int* in_sizes, int n_in,
                              void* d_out, int out_size, void* d_ws, size_t ws_size,
                              hipStream_t stream) {
    const float* emb = (const float*)d_in[0];
    const int* classes = (const int*)d_in[1];
    float* out = (float*)d_out;

    ushort* nemb = (ushort*)d_ws;                                 // 4096*128 bf16 = 1 MB
    float* gHist = (float*)((char*)d_ws + (size_t)BN * DD * sizeof(ushort));  // 200 floats

    hipMemsetAsync(gHist, 0, 2 * NSTEPS * sizeof(float), stream);

    hl_normalize<<<BN / 4, 256, 0, stream>>>(emb, nemb);

    hl_pair<<<NBLK, 256, 0, stream>>>(nemb, classes, gHist);

    hl_final<<<1, 128, 0, stream>>>(gHist, out);
}